// Round 3
// baseline (350.726 us; speedup 1.0000x reference)
//
#include <hip/hip_runtime.h>
#include <math.h>

#define IMG_W 8192
#define PATCH 32
#define NPATCH 65536      // 256*256 patches
#define NBLK   2048       // kernel A blocks: 4 waves/block, 1 strip (8 patches) per wave

// ---------------------------------------------------------------------------
// Kernel A: fused patch-mean + loss terms, streaming layout.
// Wave = one strip: patch-row ph (32 image rows), 1 KiB-wide column segment
// (8 patches). Per row the wave loads 64 consecutive float4s = 1024
// contiguous bytes (perfectly coalesced, 128B-line aligned since seg*1024).
// Per lane: 32 independent float4 loads (512 B in flight), 4 accumulator
// chains for ILP. 8-lane sub-groups own one patch (32 floats/row).
// ---------------------------------------------------------------------------
__global__ __launch_bounds__(256) void fused_patch_loss_kernel(
    const float* __restrict__ x, const float* __restrict__ tmask,
    float* __restrict__ p_pos, float* __restrict__ p_neg,
    float* __restrict__ p_cnt)
{
    const int wave  = threadIdx.x >> 6;          // 0..3
    const int lane  = threadIdx.x & 63;
    const int strip = blockIdx.x * 4 + wave;     // 0..8191
    const int ph    = strip >> 5;                // 0..255 patch-row
    const int seg   = strip & 31;                // 0..31 column segment (8 patches)

    const float* base = x + (size_t)ph * (PATCH * IMG_W)
                          + (size_t)seg * 256 + (size_t)lane * 4;

    float s0 = 0.0f, s1 = 0.0f, s2 = 0.0f, s3 = 0.0f;
#pragma unroll
    for (int r = 0; r < 32; r += 4) {
        const float4 v0 = *reinterpret_cast<const float4*>(base + (size_t)(r + 0) * IMG_W);
        const float4 v1 = *reinterpret_cast<const float4*>(base + (size_t)(r + 1) * IMG_W);
        const float4 v2 = *reinterpret_cast<const float4*>(base + (size_t)(r + 2) * IMG_W);
        const float4 v3 = *reinterpret_cast<const float4*>(base + (size_t)(r + 3) * IMG_W);
        s0 += (v0.x + v0.y) + (v0.z + v0.w);
        s1 += (v1.x + v1.y) + (v1.z + v1.w);
        s2 += (v2.x + v2.y) + (v2.z + v2.w);
        s3 += (v3.x + v3.y) + (v3.z + v3.w);
    }
    float s = (s0 + s1) + (s2 + s3);

    // 8-lane sub-group reduce -> patch sum on lanes where (lane&7)==0
    s += __shfl_down(s, 4, 64);
    s += __shfl_down(s, 2, 64);
    s += __shfl_down(s, 1, 64);

    float pos = 0.0f, neg = 0.0f, cnt = 0.0f;
    if ((lane & 7) == 0) {
        const float m = s * (1.0f / 1024.0f);
        const int patch = ph * 256 + seg * 8 + (lane >> 3);
        const float t = tmask[patch];
        // logpdf = -0.5*z^2 - log(0.04*sqrt(2*pi)); log const = -2.2999373
        const float z = (m - 0.34f) * 25.0f;
        const float logpdf = -0.5f * z * z + 2.2999373f;
        const float pterm = -logf(expf(logpdf) + 1e-6f);
        if (t >= 0.5f) { pos = pterm; cnt = 1.0f; }
        else           { neg = m * m; }
    }
    // reduce the 8 sub-group leaders (lanes 0,8,...,56): offsets 32,16,8
    pos += __shfl_down(pos, 32, 64);
    neg += __shfl_down(neg, 32, 64);
    cnt += __shfl_down(cnt, 32, 64);
    pos += __shfl_down(pos, 16, 64);
    neg += __shfl_down(neg, 16, 64);
    cnt += __shfl_down(cnt, 16, 64);
    pos += __shfl_down(pos, 8, 64);
    neg += __shfl_down(neg, 8, 64);
    cnt += __shfl_down(cnt, 8, 64);

    __shared__ float sp[4], sn[4], sc[4];
    if (lane == 0) { sp[wave] = pos; sn[wave] = neg; sc[wave] = cnt; }
    __syncthreads();

    if (threadIdx.x == 0) {
        p_pos[blockIdx.x] = (sp[0] + sp[1]) + (sp[2] + sp[3]);
        p_neg[blockIdx.x] = (sn[0] + sn[1]) + (sn[2] + sn[3]);
        p_cnt[blockIdx.x] = (sc[0] + sc[1]) + (sc[2] + sc[3]);
    }
}

// ---------------------------------------------------------------------------
// Kernel B: single-block reduction of 2048 partials x3 + finalize scalar.
// ---------------------------------------------------------------------------
__global__ __launch_bounds__(256) void finalize_reduce_kernel(
    const float* __restrict__ p_pos, const float* __restrict__ p_neg,
    const float* __restrict__ p_cnt, float* __restrict__ out)
{
    float pos = 0.0f, neg = 0.0f, cnt = 0.0f;
#pragma unroll
    for (int i = threadIdx.x; i < NBLK; i += 256) {
        pos += p_pos[i];
        neg += p_neg[i];
        cnt += p_cnt[i];
    }

#pragma unroll
    for (int off = 32; off >= 1; off >>= 1) {
        pos += __shfl_down(pos, off, 64);
        neg += __shfl_down(neg, off, 64);
        cnt += __shfl_down(cnt, off, 64);
    }

    __shared__ float sp[4], sn[4], sc[4];
    const int wave = threadIdx.x >> 6;
    const int lane = threadIdx.x & 63;
    if (lane == 0) { sp[wave] = pos; sn[wave] = neg; sc[wave] = cnt; }
    __syncthreads();

    if (threadIdx.x == 0) {
        const float P = (sp[0] + sp[1]) + (sp[2] + sp[3]);
        const float N = (sn[0] + sn[1]) + (sn[2] + sn[3]);
        const float C = (sc[0] + sc[1]) + (sc[2] + sc[3]);
        out[0] = P / C + N / ((float)NPATCH - C);
    }
}

extern "C" void kernel_launch(void* const* d_in, const int* in_sizes, int n_in,
                              void* d_out, int out_size, void* d_ws, size_t ws_size,
                              hipStream_t stream)
{
    const float* unet  = (const float*)d_in[0];   // [1,1,8192,8192] fp32
    const float* trans = (const float*)d_in[1];   // [1,256,256] fp32
    float* out = (float*)d_out;                   // scalar fp32

    float* p_pos = (float*)d_ws;                  // [2048]
    float* p_neg = p_pos + NBLK;                  // [2048]
    float* p_cnt = p_neg + NBLK;                  // [2048]

    fused_patch_loss_kernel<<<NBLK, 256, 0, stream>>>(unet, trans, p_pos, p_neg, p_cnt);
    finalize_reduce_kernel<<<1, 256, 0, stream>>>(p_pos, p_neg, p_cnt, out);
}

// Round 4
// 338.233 us; speedup vs baseline: 1.0369x; 1.0369x over previous
//
#include <hip/hip_runtime.h>
#include <math.h>

#define IMG_W 8192
#define PATCH 32
#define NPATCH 65536      // 256*256 patches
#define NBLK   2048       // kernel A blocks: 4 waves/block, 1 strip (8 patches) per wave

// ext_vector float4 so __builtin_nontemporal_load accepts it
typedef float f4 __attribute__((ext_vector_type(4)));

// ---------------------------------------------------------------------------
// Kernel A: fused patch-mean + loss terms, streaming layout, NON-TEMPORAL
// loads. The harness's 1 GiB 0xAA ws-fill right before this kernel leaves the
// 256 MiB LLC full of dirty lines; a normal (allocating) cold read forces
// ~256 MiB of writebacks during this kernel. `nt` loads read around the LLC:
// no allocation -> no dirty evictions -> ~half the HBM traffic in our window.
//
// Wave = one strip: patch-row ph (32 image rows), 1 KiB-wide column segment
// (8 patches). Per row the wave loads 64 consecutive float4s = 1 KiB
// contiguous. Per lane: 32 independent loads, 4 accumulator chains.
// ---------------------------------------------------------------------------
__global__ __launch_bounds__(256) void fused_patch_loss_kernel(
    const float* __restrict__ x, const float* __restrict__ tmask,
    float* __restrict__ p_pos, float* __restrict__ p_neg,
    float* __restrict__ p_cnt)
{
    const int wave  = threadIdx.x >> 6;          // 0..3
    const int lane  = threadIdx.x & 63;
    const int strip = blockIdx.x * 4 + wave;     // 0..8191
    const int ph    = strip >> 5;                // 0..255 patch-row
    const int seg   = strip & 31;                // 0..31 column segment (8 patches)

    const float* base = x + (size_t)ph * (PATCH * IMG_W)
                          + (size_t)seg * 256 + (size_t)lane * 4;

    float s0 = 0.0f, s1 = 0.0f, s2 = 0.0f, s3 = 0.0f;
#pragma unroll
    for (int r = 0; r < 32; r += 4) {
        const f4 v0 = __builtin_nontemporal_load(
            reinterpret_cast<const f4*>(base + (size_t)(r + 0) * IMG_W));
        const f4 v1 = __builtin_nontemporal_load(
            reinterpret_cast<const f4*>(base + (size_t)(r + 1) * IMG_W));
        const f4 v2 = __builtin_nontemporal_load(
            reinterpret_cast<const f4*>(base + (size_t)(r + 2) * IMG_W));
        const f4 v3 = __builtin_nontemporal_load(
            reinterpret_cast<const f4*>(base + (size_t)(r + 3) * IMG_W));
        s0 += (v0.x + v0.y) + (v0.z + v0.w);
        s1 += (v1.x + v1.y) + (v1.z + v1.w);
        s2 += (v2.x + v2.y) + (v2.z + v2.w);
        s3 += (v3.x + v3.y) + (v3.z + v3.w);
    }
    float s = (s0 + s1) + (s2 + s3);

    // 8-lane sub-group reduce -> patch sum on lanes where (lane&7)==0
    s += __shfl_down(s, 4, 64);
    s += __shfl_down(s, 2, 64);
    s += __shfl_down(s, 1, 64);

    float pos = 0.0f, neg = 0.0f, cnt = 0.0f;
    if ((lane & 7) == 0) {
        const float m = s * (1.0f / 1024.0f);
        const int patch = ph * 256 + seg * 8 + (lane >> 3);
        const float t = tmask[patch];
        // logpdf = -0.5*z^2 - log(0.04*sqrt(2*pi)); log const = -2.2999373
        const float z = (m - 0.34f) * 25.0f;
        const float logpdf = -0.5f * z * z + 2.2999373f;
        const float pterm = -logf(expf(logpdf) + 1e-6f);
        if (t >= 0.5f) { pos = pterm; cnt = 1.0f; }
        else           { neg = m * m; }
    }
    // reduce the 8 sub-group leaders (lanes 0,8,...,56)
    pos += __shfl_down(pos, 32, 64);
    neg += __shfl_down(neg, 32, 64);
    cnt += __shfl_down(cnt, 32, 64);
    pos += __shfl_down(pos, 16, 64);
    neg += __shfl_down(neg, 16, 64);
    cnt += __shfl_down(cnt, 16, 64);
    pos += __shfl_down(pos, 8, 64);
    neg += __shfl_down(neg, 8, 64);
    cnt += __shfl_down(cnt, 8, 64);

    __shared__ float sp[4], sn[4], sc[4];
    if (lane == 0) { sp[wave] = pos; sn[wave] = neg; sc[wave] = cnt; }
    __syncthreads();

    if (threadIdx.x == 0) {
        p_pos[blockIdx.x] = (sp[0] + sp[1]) + (sp[2] + sp[3]);
        p_neg[blockIdx.x] = (sn[0] + sn[1]) + (sn[2] + sn[3]);
        p_cnt[blockIdx.x] = (sc[0] + sc[1]) + (sc[2] + sc[3]);
    }
}

// ---------------------------------------------------------------------------
// Kernel B: single-block reduction of 2048 partials x3 + finalize scalar.
// ---------------------------------------------------------------------------
__global__ __launch_bounds__(256) void finalize_reduce_kernel(
    const float* __restrict__ p_pos, const float* __restrict__ p_neg,
    const float* __restrict__ p_cnt, float* __restrict__ out)
{
    float pos = 0.0f, neg = 0.0f, cnt = 0.0f;
#pragma unroll
    for (int i = threadIdx.x; i < NBLK; i += 256) {
        pos += p_pos[i];
        neg += p_neg[i];
        cnt += p_cnt[i];
    }

#pragma unroll
    for (int off = 32; off >= 1; off >>= 1) {
        pos += __shfl_down(pos, off, 64);
        neg += __shfl_down(neg, off, 64);
        cnt += __shfl_down(cnt, off, 64);
    }

    __shared__ float sp[4], sn[4], sc[4];
    const int wave = threadIdx.x >> 6;
    const int lane = threadIdx.x & 63;
    if (lane == 0) { sp[wave] = pos; sn[wave] = neg; sc[wave] = cnt; }
    __syncthreads();

    if (threadIdx.x == 0) {
        const float P = (sp[0] + sp[1]) + (sp[2] + sp[3]);
        const float N = (sn[0] + sn[1]) + (sn[2] + sn[3]);
        const float C = (sc[0] + sc[1]) + (sc[2] + sc[3]);
        out[0] = P / C + N / ((float)NPATCH - C);
    }
}

extern "C" void kernel_launch(void* const* d_in, const int* in_sizes, int n_in,
                              void* d_out, int out_size, void* d_ws, size_t ws_size,
                              hipStream_t stream)
{
    const float* unet  = (const float*)d_in[0];   // [1,1,8192,8192] fp32
    const float* trans = (const float*)d_in[1];   // [1,256,256] fp32
    float* out = (float*)d_out;                   // scalar fp32

    float* p_pos = (float*)d_ws;                  // [2048]
    float* p_neg = p_pos + NBLK;                  // [2048]
    float* p_cnt = p_neg + NBLK;                  // [2048]

    fused_patch_loss_kernel<<<NBLK, 256, 0, stream>>>(unet, trans, p_pos, p_neg, p_cnt);
    finalize_reduce_kernel<<<1, 256, 0, stream>>>(p_pos, p_neg, p_cnt, out);
}